// Round 18
// baseline (197.974 us; speedup 1.0000x reference)
//
#include <hip/hip_runtime.h>

// out[b,c,y,x] = sum_{kdy,kdx in [0,9)} corr[b, kdy*9+kdx, y+4-kdy, x+4-kdx] * feat[b,c, y+4-kdy, x+4-kdx]
// R18 = R17 + (1) XOR-swizzled M_sh (kills the 8-way bank conflict on M reads),
//       (2) fused single-launch prepass (mband blocks + feat-bf16 streaming blocks).
//   featb[b,c,sy,sx] = bf16(feat)
//   mband[(b*96+sy)*9+kdy][x][o] = bf16(corr[b, kdy*9+(x+8-(kb+o)), sy, kb+o-4]), 0 OOB,
//     kb(x) = x<80 ? x&~15 : 72
//   main: per (b,y): out[C,X] = sum_kdy A[C,K] * M[K,X] via 16x16x32 bf16 MFMA.
//   M_sh swizzle: uint4 of logical dword-col c at row r stored at p = c ^ (((r>>1)&3)<<2).

#define RR 4
#define DD 9
#define D2 81
#define Bn 16
#define Cn 256
#define Hn 96
#define Wn 96
#define HWn (Hn*Wn)
#define NTH 512
#define KW  104           // A row stride (ushort); 52 dwords -> 8-period banks, ~2-way (free)
#define MW  32            // M window; swizzled -> 2-way (free)

typedef __attribute__((ext_vector_type(8))) short bf16x8;
typedef __attribute__((ext_vector_type(4))) float f32x4;

__device__ __forceinline__ uint cvt_pk(float lo, float hi) {
    uint r;
    asm("v_cvt_pk_bf16_f32 %0, %1, %2" : "=v"(r) : "v"(lo), "v"(hi));
    return r;
}
__device__ __forceinline__ ushort f2bf(float f) {
    uint u = __float_as_uint(f);
    return (ushort)((u + 0x7FFFu + ((u >> 16) & 1u)) >> 16);
}

// ---- fused prepass: blocks [0,1536) build mband, blocks [1536,4096) convert feat ----
#define PREP_MB (Bn*Hn)          // 1536
#define PREP_FT 2560
__global__ __launch_bounds__(384)
void prep_all_kernel(const float* __restrict__ feat, const float* __restrict__ corr,
                     ushort* __restrict__ featb, ushort* __restrict__ mband)
{
    if (blockIdx.x < PREP_MB) {
        const int s  = blockIdx.x;               // b*Hn + sy
        const int sy = s % Hn, b = s / Hn;
        const float* cb = corr + (size_t)b * D2 * HWn + (size_t)sy * Wn;
        const int t   = threadIdx.x;             // 384 = 96 x * 4 octets
        const int x   = t >> 2, oct = t & 3;
        const int kb  = (x >= 80) ? 72 : (x & ~15);
        ushort* mbase = mband + ((size_t)s * DD) * (Wn * MW) + x * MW + oct * 8;
        #pragma unroll 1
        for (int kdy = 0; kdy < DD; ++kdy) {
            ushort v[8];
            #pragma unroll
            for (int i = 0; i < 8; ++i) {
                int o   = oct * 8 + i;
                int sxp = kb + o;
                int kdx = x + 2 * RR - sxp;
                float f = 0.f;
                if (kdx >= 0 && kdx < DD && sxp >= RR && sxp < Wn + RR)
                    f = cb[(size_t)(kdy * DD + kdx) * HWn + (sxp - RR)];
                v[i] = f2bf(f);
            }
            *reinterpret_cast<uint4*>(mbase + (size_t)kdy * (Wn * MW)) =
                make_uint4((uint)v[0] | ((uint)v[1] << 16), (uint)v[2] | ((uint)v[3] << 16),
                           (uint)v[4] | ((uint)v[5] << 16), (uint)v[6] | ((uint)v[7] << 16));
        }
    } else {
        const int n8 = Bn * Cn * HWn / 8;
        const float4* src = reinterpret_cast<const float4*>(feat);
        uint4* dst = reinterpret_cast<uint4*>(featb);
        for (int i = (blockIdx.x - PREP_MB) * 384 + threadIdx.x; i < n8; i += PREP_FT * 384) {
            float4 a = src[2 * i], c = src[2 * i + 1];
            dst[i] = make_uint4(cvt_pk(a.x, a.y), cvt_pk(a.z, a.w), cvt_pk(c.x, c.y), cvt_pk(c.z, c.w));
        }
    }
}

// ---- main (R17 structure + swizzled M_sh) ----
__global__ __launch_bounds__(NTH, 2)
void corrT18_kernel(const ushort* __restrict__ featb, const ushort* __restrict__ mband,
                    float* __restrict__ out)
{
    __shared__ ushort A_sh[Cn][KW];        // 53248 B, single buffer
    __shared__ ushort M_sh[2][Wn][MW];     // 12288 B, double buffer (total 64 KB)

    // XCD-chunked dispatch: y contiguous per XCD (grid 1536 = 8*192)
    int bid = blockIdx.x;
    int L   = (bid & 7) * 192 + (bid >> 3);
    int y   = L % Hn;
    int b   = L / Hn;

    const int tid  = threadIdx.x;
    const int lane = tid & 63;
    const int wid  = tid >> 6;
    const int mrow = lane & 15;
    const int kq   = lane >> 4;
    const int kgrp = kq << 3;             // ushort K sub-base 0,8,16,24

    for (int i = tid; i < Cn; i += NTH) {  // zero A pads once
        *reinterpret_cast<uint2*>(&A_sh[i][0])   = make_uint2(0u, 0u);
        *reinterpret_cast<uint2*>(&A_sh[i][100]) = make_uint2(0u, 0u);
    }
    __syncthreads();

    const int klo = max(0, y - (Hn - 1 - RR));
    const int khi = min(DD - 1, y + RR);

    const int ac  = tid >> 1;             // 2 threads per channel row
    const int seg = tid & 1;              // 48-element half row
    const ushort* fb_base = featb + (((size_t)b * Cn + ac) * Hn) * (size_t)Wn + seg * 48;

    // M_sh swizzled uint4 store index for writer slot w (w<384): row=w>>2, c=(w&3)*4 dwords
    const int mwrow = tid >> 2;
    const int mwp   = ((tid & 3) << 2) ^ (((mwrow >> 1) & 3) << 2);   // dwords
    const int mwidx = mwrow * 4 + (mwp >> 2);                          // uint4 index

    // ---- prologue: stage A + M for kdy = klo ----
    {
        const int sy = y + RR - klo;
        const uint4* src = reinterpret_cast<const uint4*>(fb_base + (size_t)sy * Wn);
        #pragma unroll
        for (int i = 0; i < 6; ++i) {
            uint4 v = src[i];
            uint2* d = reinterpret_cast<uint2*>(&A_sh[ac][4 + seg * 48 + i * 8]);
            d[0] = make_uint2(v.x, v.y);
            d[1] = make_uint2(v.z, v.w);
        }
        const ushort* ms = mband + (((size_t)b * Hn + sy) * DD + klo) * (size_t)(Wn * MW);
        if (tid < 384)
            reinterpret_cast<uint4*>(&M_sh[0][0][0])[mwidx] = reinterpret_cast<const uint4*>(ms)[tid];
    }
    __syncthreads();

    f32x4 acc[2][6];
    #pragma unroll
    for (int ct = 0; ct < 2; ++ct)
        #pragma unroll
        for (int t6 = 0; t6 < 6; ++t6)
            acc[ct][t6] = (f32x4){0.f, 0.f, 0.f, 0.f};

    #pragma unroll 1
    for (int kk = klo; kk <= khi; ++kk) {
        const int pb = (kk - klo) & 1;
        const bool vn = (kk + 1 <= khi);
        const int syn = y + RR - (kk + 1);

        // -- T14 issue-early: next A row + next M slice held in regs across MFMA --
        uint4 a0, a1, a2, a3, a4, a5;
        uint4 mvv = make_uint4(0u, 0u, 0u, 0u);
        if (vn) {
            const uint4* src = reinterpret_cast<const uint4*>(fb_base + (size_t)syn * Wn);
            a0 = src[0]; a1 = src[1]; a2 = src[2]; a3 = src[3]; a4 = src[4]; a5 = src[5];
            const ushort* ms = mband + (((size_t)b * Hn + syn) * DD + (kk + 1)) * (size_t)(Wn * MW);
            if (tid < 384) mvv = reinterpret_cast<const uint4*>(ms)[tid];
        }

        // -- MFMA phase: 12 x v_mfma_f32_16x16x32_bf16 per wave --
        #pragma unroll
        for (int t6 = 0; t6 < 6; ++t6) {
            const int kb = (t6 == 5) ? 72 : t6 * 16;
            const int mr = t6 * 16 + mrow;
            const int mp = kgrp ^ (((mr >> 1) & 3) << 3);        // swizzled ushort col
            uint4 bw = *reinterpret_cast<const uint4*>(&M_sh[pb][mr][mp]);
            bf16x8 bfr = *reinterpret_cast<bf16x8*>(&bw);
            #pragma unroll
            for (int ct = 0; ct < 2; ++ct) {
                bf16x8 afr = *reinterpret_cast<const bf16x8*>(&A_sh[wid * 32 + ct * 16 + mrow][kb + kgrp]);
                acc[ct][t6] = __builtin_amdgcn_mfma_f32_16x16x32_bf16(afr, bfr, acc[ct][t6], 0, 0, 0);
            }
        }
        __syncthreads();                  // done reading A_sh / M_sh[pb]

        // -- write-late --
        if (vn) {
            uint2* d0 = reinterpret_cast<uint2*>(&A_sh[ac][4 + seg * 48]);
            d0[0] = make_uint2(a0.x, a0.y); d0[1] = make_uint2(a0.z, a0.w);
            d0[2] = make_uint2(a1.x, a1.y); d0[3] = make_uint2(a1.z, a1.w);
            d0[4] = make_uint2(a2.x, a2.y); d0[5] = make_uint2(a2.z, a2.w);
            d0[6] = make_uint2(a3.x, a3.y); d0[7] = make_uint2(a3.z, a3.w);
            d0[8] = make_uint2(a4.x, a4.y); d0[9] = make_uint2(a4.z, a4.w);
            d0[10] = make_uint2(a5.x, a5.y); d0[11] = make_uint2(a5.z, a5.w);
            if (tid < 384)
                reinterpret_cast<uint4*>(&M_sh[pb ^ 1][0][0])[mwidx] = mvv;
        }
        __syncthreads();
    }

    // ---- epilogue: C/D layout col=lane&15 (x), row=(lane>>4)*4+r (c) — R11/R15-verified ----
    const int csub = kq << 2;
    #pragma unroll
    for (int ct = 0; ct < 2; ++ct)
        #pragma unroll
        for (int t6 = 0; t6 < 6; ++t6)
            #pragma unroll
            for (int r = 0; r < 4; ++r)
                out[(((size_t)b * Cn + wid * 32 + ct * 16 + csub + r) * Hn + y) * Wn + t6 * 16 + mrow]
                    = acc[ct][t6][r];
}

// ---- fallback (ws too small): proven R8 fp32 scalar kernel ----
#define NTXf 12
#define NTCf 32
#define NTHf (NTXf*NTCf)
#define LWf  100
#define LW4f (LWf/4)
__global__ __launch_bounds__(NTHf, 6)
void corrT8_kernel(const float* __restrict__ corr, const float* __restrict__ feat,
                   float* __restrict__ out)
{
    __shared__ float lds[D2 * LWf];
    int bid = blockIdx.x;
    int sw  = (bid & 7) * (gridDim.x >> 3) + (bid >> 3);
    int cg  = sw & 3;
    int y   = (sw >> 2) % Hn;
    int b   = sw / (4 * Hn);
    const int tid = threadIdx.x;
    const float* corrb = corr + (size_t)b * D2 * HWn;
    for (int idx = tid; idx < D2 * LW4f; idx += NTHf) {
        int row = idx / LW4f, c4 = idx - row * LW4f;
        int kdy = row / DD, kdx = row - kdy * DD;
        int sy  = y + RR - kdy;
        float4 v = make_float4(0.f, 0.f, 0.f, 0.f);
        if (sy >= 0 && sy < Hn) {
            const float* src = corrb + (size_t)row * HWn + sy * Wn;
            #pragma unroll
            for (int e = 0; e < 4; ++e) {
                int sx = c4 * 4 + e - kdx;
                if (sx >= 0 && sx < Wn) (&v.x)[e] = src[sx];
            }
        }
        *reinterpret_cast<float4*>(&lds[row * LWf + c4 * 4]) = v;
    }
    __syncthreads();
    const int tx = tid % NTXf, tc = tid / NTXf;
    const int x0 = tx * 8, c0 = cg * 64 + tc * 2;
    const float* featp = feat + ((size_t)b * Cn + c0) * HWn;
    float acc[2][8] = {};
    const int klo = max(0, y - (Hn - 1 - RR)), khi = min(DD - 1, y + RR);
    #pragma unroll 1
    for (int kdy = klo; kdy <= khi; ++kdy) {
        int sy = y + RR - kdy;
        float f[2][16];
        const float* frow = featp + sy * Wn + x0 - RR;
        #pragma unroll
        for (int c = 0; c < 2; ++c) {
            const float* p = frow + (size_t)c * HWn;
            float4 f0 = (tx == 0) ? make_float4(0,0,0,0) : *reinterpret_cast<const float4*>(p);
            float4 f1 = *reinterpret_cast<const float4*>(p + 4);
            float4 f2 = *reinterpret_cast<const float4*>(p + 8);
            float4 f3 = (tx == NTXf-1) ? make_float4(0,0,0,0) : *reinterpret_cast<const float4*>(p + 12);
            f[c][0]=f0.x; f[c][1]=f0.y; f[c][2]=f0.z; f[c][3]=f0.w;
            f[c][4]=f1.x; f[c][5]=f1.y; f[c][6]=f1.z; f[c][7]=f1.w;
            f[c][8]=f2.x; f[c][9]=f2.y; f[c][10]=f2.z; f[c][11]=f2.w;
            f[c][12]=f3.x; f[c][13]=f3.y; f[c][14]=f3.z; f[c][15]=f3.w;
        }
        const float4* base = reinterpret_cast<const float4*>(lds) + (tx * 2 + 1) + kdy * DD * LW4f;
        float4 ca = base[0], cb = base[1];
        #pragma unroll
        for (int kdx = 0; kdx < DD; ++kdx) {
            float4 na = ca, nb = cb;
            if (kdx < DD - 1) { na = base[(kdx+1)*LW4f]; nb = base[(kdx+1)*LW4f + 1]; }
            float cv[8] = {ca.x, ca.y, ca.z, ca.w, cb.x, cb.y, cb.z, cb.w};
            #pragma unroll
            for (int c = 0; c < 2; ++c)
                #pragma unroll
                for (int j = 0; j < 8; ++j)
                    acc[c][j] = fmaf(cv[j], f[c][j + 8 - kdx], acc[c][j]);
            ca = na; cb = nb;
        }
    }
    float* ob = out + ((size_t)b * Cn + c0) * HWn + (size_t)y * Wn + x0;
    #pragma unroll
    for (int c = 0; c < 2; ++c) {
        *reinterpret_cast<float4*>(ob + (size_t)c * HWn)     = make_float4(acc[c][0], acc[c][1], acc[c][2], acc[c][3]);
        *reinterpret_cast<float4*>(ob + (size_t)c * HWn + 4) = make_float4(acc[c][4], acc[c][5], acc[c][6], acc[c][7]);
    }
}

extern "C" void kernel_launch(void* const* d_in, const int* in_sizes, int n_in,
                              void* d_out, int out_size, void* d_ws, size_t ws_size,
                              hipStream_t stream)
{
    const float* corr = (const float*)d_in[0];   // [16,81,96,96]
    const float* feat = (const float*)d_in[1];   // [16,256,96,96]
    float* out = (float*)d_out;                  // [16,256,96,96]

    const size_t needF = (size_t)Bn * Cn * HWn * 2;              // 75,497,472
    const size_t needM = (size_t)Bn * Hn * DD * Wn * MW * 2;     // 84,934,656

    if (ws_size >= needF + needM) {
        ushort* featb = (ushort*)d_ws;
        ushort* mband = (ushort*)((char*)d_ws + needF);
        prep_all_kernel<<<PREP_MB + PREP_FT, 384, 0, stream>>>(feat, corr, featb, mband);
        corrT18_kernel<<<Bn * Hn, NTH, 0, stream>>>(featb, mband, out);
    } else {
        corrT8_kernel<<<Bn * Hn * 4, NTHf, 0, stream>>>(corr, feat, out);
    }
}